// Round 4
// baseline (695.387 us; speedup 1.0000x reference)
//
#include <hip/hip_runtime.h>
#include <hip/hip_bf16.h>
#include <math.h>

typedef unsigned char u8;
typedef unsigned int  u32;

#define N_    32
#define C1    128
#define H1    56
#define W1    56
#define HW1   (H1*W1)        // 3136
#define CHW1  (C1*HW1)       // 401408
#define C2    256
#define HO    28
#define WO    28
#define OHW   (HO*WO)        // 784
#define R_    (N_*OHW)       // 25088

// ---------------- workspace layout (bytes) ----------------
#define OFF_BN1S   ((size_t)0)          // 128 f64
#define OFF_BN1Q   ((size_t)1024)       // 128 f64
#define OFF_BN2S   ((size_t)2048)       // 256 f64
#define OFF_BN2Q   ((size_t)4096)       // 256 f64
#define OFF_POOL   ((size_t)6144)       // 32*256 f32 -> ends 38912  (memset region: 0..38912)
#define OFF_SCALE1 ((size_t)38912)      // 128 f64
#define OFF_SHIFT1 ((size_t)39936)
#define OFF_SCALE2 ((size_t)40960)      // 256 f64
#define OFF_SHIFT2 ((size_t)43008)
#define OFF_GATE   ((size_t)45056)      // 32*256 f32
#define OFF_CODE1  ((size_t)77824)      // 25088*128 u8
#define OFF_CODES  ((size_t)3289088)    // 25088*32 u8
#define OFF_CODE2  ((size_t)4091904)    // 25088*256 u8
#define OFF_OUT1   ((size_t)10514432)   // 25088*256 f64 (encode-feeding: keep f64!)
#define OFF_SC     ((size_t)61894656)   // 25088*256 f32
#define OFF_OUT2   ((size_t)87584768)   // 25088*256 f32 -> ends 113274880

// ---------------- BN1 stats (f64) ----------------
__global__ __launch_bounds__(256) void k_bn1_stats(const float* __restrict__ x,
                                                   double* __restrict__ s1, double* __restrict__ q1) {
  __shared__ double rs[256], rq[256];
  int b = blockIdx.x; int c = b >> 3, chunk = b & 7;
  int tid = threadIdx.x;
  double s = 0.0, q = 0.0;
  for (int nn = chunk*4; nn < chunk*4 + 4; ++nn) {
    const float* p = x + (size_t)nn*CHW1 + (size_t)c*HW1;
    for (int i = tid; i < HW1; i += 256) { double v = (double)p[i]; s += v; q += v*v; }
  }
  rs[tid] = s; rq[tid] = q; __syncthreads();
  for (int st = 128; st > 0; st >>= 1) {
    if (tid < st) { rs[tid] += rs[tid+st]; rq[tid] += rq[tid+st]; }
    __syncthreads();
  }
  if (tid == 0) { atomicAdd(&s1[c], rs[0]); atomicAdd(&q1[c], rq[0]); }
}

// ---------------- BN finalize -> per-channel scale/shift (f64) ----------------
__global__ __launch_bounds__(256) void k_fin(const double* __restrict__ s, const double* __restrict__ q,
                                             const float* __restrict__ g, const float* __restrict__ b,
                                             double* __restrict__ scale, double* __restrict__ shift,
                                             int nc, double cnt) {
  int c = blockIdx.x*blockDim.x + threadIdx.x;
  if (c >= nc) return;
  double m   = s[c] / cnt;
  double var = q[c] / cnt - m*m;
  double istd = 1.0 / sqrt(var + 1e-5);
  double sc = istd * (double)g[c];
  scale[c] = sc;
  shift[c] = (double)b[c] - m*sc;
}

// ---------------- encode conv1 (+shortcut), reads x with on-the-fly bn_relu ----------------
__global__ __launch_bounds__(256) void k_enc1(const float* __restrict__ x,
                                              const int* __restrict__ sd1, const float* __restrict__ thr1,
                                              const int* __restrict__ sds, const float* __restrict__ thrs,
                                              const double* __restrict__ scale1, const double* __restrict__ shift1,
                                              u8* __restrict__ code1, u8* __restrict__ codes) {
  __shared__ double lsc[C1], lsh[C1];
  __shared__ float lthr[32*15];
  __shared__ u8 lsd[32][4];
  int tid = threadIdx.x;
  int y = blockIdx.y;                    // 0..3: conv1 channel chunks; 4: shortcut
  int cbase = (y < 4) ? y*32 : 0;
  if (tid < C1) { lsc[tid] = scale1[tid]; lsh[tid] = shift1[tid]; }
  if (y < 4) {
    for (int i = tid; i < 32*15; i += 256) lthr[i] = thr1[cbase*15 + i];
    if (tid < 32) for (int j = 0; j < 4; ++j) lsd[tid][j] = (u8)sd1[(cbase+tid)*4 + j];
  } else {
    for (int i = tid; i < 32*15; i += 256) lthr[i] = thrs[i];
    if (tid < 32) for (int j = 0; j < 4; ++j) lsd[tid][j] = (u8)sds[tid*4 + j];
  }
  __syncthreads();
  int r = blockIdx.x*256 + tid;
  int n = r / OHW; int rem = r % OHW; int ho = rem / WO; int wo = rem % WO;
  const float* xn = x + (size_t)n*CHW1;
  if (y < 4) {
    for (int ci = 0; ci < 32; ++ci) {
      int c = cbase + ci;
      double sc = lsc[c], sh = lsh[c];
      int code = 0;
      #pragma unroll
      for (int t = 0; t < 4; ++t) {
        int sd = lsd[ci][t];             // 0..8
        int kh = sd / 3, kw = sd - kh*3;
        int ih = 2*ho + kh - 1, iw = 2*wo + kw - 1;
        double thr = (double)lthr[ci*15 + ((1<<t)-1) + code];
        int bit;
        if ((unsigned)ih < (unsigned)H1 && (unsigned)iw < (unsigned)W1) {
          double z = fma((double)xn[c*HW1 + ih*W1 + iw], sc, sh);
          z = z > 0.0 ? z : 0.0;         // relu
          bit = (z > thr) ? 1 : 0;
        } else {
          bit = (0.0 > thr) ? 1 : 0;     // zero padding participates in compare
        }
        code = code + code + bit;
      }
      code1[(size_t)r*C1 + c] = (u8)code;
    }
  } else {
    int base = (2*ho)*W1 + 2*wo;
    for (int ci = 0; ci < 32; ++ci) {
      int code = 0;
      #pragma unroll
      for (int t = 0; t < 4; ++t) {
        int sd = lsd[ci][t];             // 0..3 -> channel within group
        int ch = ci*4 + sd;
        double thr = (double)lthr[ci*15 + ((1<<t)-1) + code];
        double z = fma((double)xn[ch*HW1 + base], lsc[ch], lsh[ch]);
        z = z > 0.0 ? z : 0.0;
        int bit = (z > thr) ? 1 : 0;
        code = code + code + bit;
      }
      codes[(size_t)r*32 + ci] = (u8)code;
    }
  }
}

// ---------------- gather conv1 + shortcut: wave per pixel, lane = 4 out channels ----------------
__global__ __launch_bounds__(256) void k_gather1(const u8* __restrict__ code1, const u8* __restrict__ codes,
                                                 const float* __restrict__ lut1, const float* __restrict__ luts,
                                                 double* __restrict__ out1, float* __restrict__ sc) {
  int l = threadIdx.x & 63;
  int r = blockIdx.x*4 + (threadIdx.x >> 6);
  const u32* cp = (const u32*)(code1 + (size_t)r*C1);
  const float4* L = (const float4*)lut1;
  double a0=0,a1=0,a2=0,a3=0;
  #pragma unroll 4
  for (int w = 0; w < 32; ++w) {
    u32 cv = cp[w];
    #pragma unroll
    for (int j = 0; j < 4; ++j) {
      int c = w*4 + j;
      int code = (cv >> (8*j)) & 15;
      float4 v = L[((c*16 + code) << 6) + l];
      a0 += (double)v.x; a1 += (double)v.y; a2 += (double)v.z; a3 += (double)v.w;
    }
  }
  float b0=0,b1=0,b2=0,b3=0;
  const u32* cps = (const u32*)(codes + (size_t)r*32);
  const float4* Ls = (const float4*)luts;
  #pragma unroll
  for (int w = 0; w < 8; ++w) {
    u32 cv = cps[w];
    #pragma unroll
    for (int j = 0; j < 4; ++j) {
      int c = w*4 + j;
      int code = (cv >> (8*j)) & 15;
      float4 v = Ls[((c*16 + code) << 6) + l];
      b0 += v.x; b1 += v.y; b2 += v.z; b3 += v.w;
    }
  }
  size_t o = (size_t)r*C2 + l*4;
  double2 d0; d0.x=a0; d0.y=a1;
  double2 d1; d1.x=a2; d1.y=a3;
  *(double2*)(out1 + o)     = d0;
  *(double2*)(out1 + o + 2) = d1;
  float4 bb; bb.x=b0; bb.y=b1; bb.z=b2; bb.w=b3;
  *(float4*)(sc + o) = bb;
}

// ---------------- BN2 stats over out1 (f64, NHWC) ----------------
__global__ __launch_bounds__(256) void k_bn2_stats(const double* __restrict__ out1,
                                                   double* __restrict__ s2, double* __restrict__ q2) {
  int o = threadIdx.x;
  int r0 = blockIdx.x * 128;
  double s = 0.0, q = 0.0;
  for (int j = 0; j < 128; ++j) {
    double v = out1[(size_t)(r0 + j)*C2 + o];
    s += v; q += v*v;
  }
  atomicAdd(&s2[o], s); atomicAdd(&q2[o], q);
}

// ---------------- encode conv2 from f64 out1 (on-the-fly bn_relu) ----------------
__global__ __launch_bounds__(256) void k_enc2(const double* __restrict__ out1,
                                              const int* __restrict__ sd2, const float* __restrict__ thr2,
                                              const double* __restrict__ scale2, const double* __restrict__ shift2,
                                              u8* __restrict__ code2) {
  __shared__ float lthr[C2*15];
  __shared__ u8 lsd[C2][4];
  __shared__ double lsc[C2], lsh[C2];
  int tid = threadIdx.x;
  for (int i = tid; i < C2*15; i += 256) lthr[i] = thr2[i];
  for (int j = 0; j < 4; ++j) lsd[tid][j] = (u8)sd2[tid*4 + j];
  lsc[tid] = scale2[tid]; lsh[tid] = shift2[tid];
  __syncthreads();
  int c = tid;
  double scv = lsc[c], shv = lsh[c];
  int r0 = blockIdx.x*8;
  for (int rr = 0; rr < 8; ++rr) {
    int r = r0 + rr;
    int n = r / OHW; int rem = r % OHW; int ho = rem / WO; int wo = rem % WO;
    const double* on = out1 + (size_t)n*OHW*C2;
    int code = 0;
    #pragma unroll
    for (int t = 0; t < 4; ++t) {
      int sd = lsd[c][t];
      int kh = sd / 3, kw = sd - kh*3;
      int h = ho + kh - 1, w = wo + kw - 1;
      double thr = (double)lthr[c*15 + ((1<<t)-1) + code];
      int bit;
      if ((unsigned)h < (unsigned)HO && (unsigned)w < (unsigned)WO) {
        double z = fma(on[(size_t)(h*WO + w)*C2 + c], scv, shv);
        z = z > 0.0 ? z : 0.0;
        bit = (z > thr) ? 1 : 0;
      } else {
        bit = (0.0 > thr) ? 1 : 0;
      }
      code = code + code + bit;
    }
    code2[(size_t)r*C2 + c] = (u8)code;
  }
}

// ---------------- gather conv2: wave per pixel ----------------
__global__ __launch_bounds__(256) void k_gather2(const u8* __restrict__ code2,
                                                 const float* __restrict__ lut2, float* __restrict__ out2) {
  int l = threadIdx.x & 63;
  int r = blockIdx.x*4 + (threadIdx.x >> 6);
  const u32* cp = (const u32*)(code2 + (size_t)r*C2);
  const float4* L = (const float4*)lut2;
  float a0=0,a1=0,a2=0,a3=0;
  #pragma unroll 4
  for (int w = 0; w < 64; ++w) {
    u32 cv = cp[w];
    #pragma unroll
    for (int j = 0; j < 4; ++j) {
      int c = w*4 + j;
      int code = (cv >> (8*j)) & 15;
      float4 v = L[((c*16 + code) << 6) + l];
      a0 += v.x; a1 += v.y; a2 += v.z; a3 += v.w;
    }
  }
  float4 res; res.x=a0; res.y=a1; res.z=a2; res.w=a3;
  *(float4*)(out2 + (size_t)r*C2 + l*4) = res;
}

// ---------------- global average pool (partial sums via atomics) ----------------
__global__ __launch_bounds__(256) void k_pool(const float* __restrict__ out2, float* __restrict__ pool) {
  int n = blockIdx.x, seg = blockIdx.y, o = threadIdx.x;
  float s = 0.0f;
  int p0 = seg*112;
  for (int p = p0; p < p0 + 112; ++p) s += out2[(size_t)(n*OHW + p)*C2 + o];
  atomicAdd(&pool[n*C2 + o], s);
}

// ---------------- SE gate: fc1 -> relu -> fc2 -> sigmoid ----------------
__global__ __launch_bounds__(256) void k_se(const float* __restrict__ pool,
                                            const float* __restrict__ w1, const float* __restrict__ b1f,
                                            const float* __restrict__ w2, const float* __restrict__ b2f,
                                            float* __restrict__ gate) {
  __shared__ float lp[C2];
  __shared__ float lh[16];
  int n = blockIdx.x, tid = threadIdx.x;
  lp[tid] = pool[n*C2 + tid] * (1.0f/(float)OHW);
  __syncthreads();
  if (tid < 16) {
    float s = b1f[tid];
    for (int c = 0; c < C2; ++c) s += lp[c]*w1[tid*C2 + c];
    lh[tid] = s > 0.0f ? s : 0.0f;
  }
  __syncthreads();
  float s = b2f[tid];
  #pragma unroll
  for (int i = 0; i < 16; ++i) s += lh[i]*w2[tid*16 + i];
  gate[n*C2 + tid] = 1.0f/(1.0f + expf(-s));
}

// ---------------- final: out = out2*gate + shortcut, NHWC -> NCHW ----------------
__global__ __launch_bounds__(256) void k_final(const float* __restrict__ out2, const float* __restrict__ scv,
                                               const float* __restrict__ gate, float* __restrict__ outp) {
  int idx = blockIdx.x*256 + threadIdx.x;
  int w = idx % WO; int t1 = idx / WO; int h = t1 % HO; int t2 = t1 / HO;
  int o = t2 & 255; int n = t2 >> 8;
  size_t rc = (size_t)(n*OHW + h*WO + w)*C2 + o;
  outp[idx] = out2[rc]*gate[n*C2 + o] + scv[rc];
}

extern "C" void kernel_launch(void* const* d_in, const int* in_sizes, int n_in,
                              void* d_out, int out_size, void* d_ws, size_t ws_size,
                              hipStream_t stream) {
  const float* x     = (const float*)d_in[0];
  const float* bn1_g = (const float*)d_in[1];
  const float* bn1_b = (const float*)d_in[2];
  const float* bn2_g = (const float*)d_in[3];
  const float* bn2_b = (const float*)d_in[4];
  const float* thr1  = (const float*)d_in[5];
  const float* lut1  = (const float*)d_in[6];
  const float* thr2  = (const float*)d_in[7];
  const float* lut2  = (const float*)d_in[8];
  const float* thr_s = (const float*)d_in[9];
  const float* lut_s = (const float*)d_in[10];
  const float* fc1_w = (const float*)d_in[11];
  const float* fc1_b = (const float*)d_in[12];
  const float* fc2_w = (const float*)d_in[13];
  const float* fc2_b = (const float*)d_in[14];
  const int*   sd1   = (const int*)d_in[15];
  const int*   sd2   = (const int*)d_in[16];
  const int*   sd_s  = (const int*)d_in[17];

  char* ws = (char*)d_ws;
  double* bn1s  = (double*)(ws + OFF_BN1S);
  double* bn1q  = (double*)(ws + OFF_BN1Q);
  double* bn2s  = (double*)(ws + OFF_BN2S);
  double* bn2q  = (double*)(ws + OFF_BN2Q);
  float*  pool  = (float*)(ws + OFF_POOL);
  double* scale1= (double*)(ws + OFF_SCALE1);
  double* shift1= (double*)(ws + OFF_SHIFT1);
  double* scale2= (double*)(ws + OFF_SCALE2);
  double* shift2= (double*)(ws + OFF_SHIFT2);
  float*  gate  = (float*)(ws + OFF_GATE);
  u8*     code1 = (u8*)(ws + OFF_CODE1);
  u8*     codes = (u8*)(ws + OFF_CODES);
  u8*     code2 = (u8*)(ws + OFF_CODE2);
  double* out1  = (double*)(ws + OFF_OUT1);
  float*  scb   = (float*)(ws + OFF_SC);
  float*  out2  = (float*)(ws + OFF_OUT2);
  float*  outp  = (float*)d_out;

  // zero the accumulators (bn sums + pool); ws is poisoned before every call
  hipMemsetAsync(ws, 0, 38912, stream);

  k_bn1_stats<<<1024, 256, 0, stream>>>(x, bn1s, bn1q);
  k_fin<<<1, 128, 0, stream>>>(bn1s, bn1q, bn1_g, bn1_b, scale1, shift1, C1, (double)(N_*HW1));
  k_enc1<<<dim3(98, 5), 256, 0, stream>>>(x, sd1, thr1, sd_s, thr_s, scale1, shift1, code1, codes);
  k_gather1<<<R_/4, 256, 0, stream>>>(code1, codes, lut1, lut_s, out1, scb);
  k_bn2_stats<<<196, 256, 0, stream>>>(out1, bn2s, bn2q);
  k_fin<<<1, 256, 0, stream>>>(bn2s, bn2q, bn2_g, bn2_b, scale2, shift2, C2, (double)R_);
  k_enc2<<<R_/8, 256, 0, stream>>>(out1, sd2, thr2, scale2, shift2, code2);
  k_gather2<<<R_/4, 256, 0, stream>>>(code2, lut2, out2);
  k_pool<<<dim3(N_, 7), 256, 0, stream>>>(out2, pool);
  k_se<<<N_, 256, 0, stream>>>(pool, fc1_w, fc1_b, fc2_w, fc2_b, gate);
  k_final<<<(int)((size_t)N_*C2*OHW/256), 256, 0, stream>>>(out2, scb, gate, outp);
}

// Round 8
// 643.807 us; speedup vs baseline: 1.0801x; 1.0801x over previous
//
#include <hip/hip_runtime.h>
#include <hip/hip_bf16.h>
#include <math.h>

typedef unsigned char u8;
typedef unsigned int  u32;
typedef unsigned long long u64;

#define N_    32
#define C1    128
#define H1    56
#define W1    56
#define HW1   (H1*W1)        // 3136
#define CHW1  (C1*HW1)       // 401408
#define C2    256
#define HO    28
#define WO    28
#define OHW   (HO*WO)        // 784
#define R_    (N_*OHW)       // 25088

// ---------------- workspace layout (bytes) ----------------
#define OFF_BN1S   ((size_t)0)          // 128 f64
#define OFF_BN1Q   ((size_t)1024)       // 128 f64
#define OFF_BN2S   ((size_t)2048)       // 256 f64
#define OFF_BN2Q   ((size_t)4096)       // 256 f64
#define OFF_POOL   ((size_t)6144)       // 32*256 f32 -> ends 38912  (memset region 0..38912)
#define OFF_SCALE1 ((size_t)38912)      // 128 f64
#define OFF_SHIFT1 ((size_t)39936)
#define OFF_SCALE2 ((size_t)40960)      // 256 f64
#define OFF_SHIFT2 ((size_t)43008)
#define OFF_GATE   ((size_t)45056)      // 32*256 f32 -> ends 77824
#define OFF_C1P    ((size_t)77824)      // code1 nibble-packed: 25088*64  -> ends 1683456
#define OFF_CS     ((size_t)1683456)    // shortcut codes u8:   25088*32  -> ends 2486272
#define OFF_LS16   ((size_t)2486272)    // lut_s bf16: 32*16*256*2        -> ends 2748416
#define OFF_L216   ((size_t)2748416)    // lut2  bf16: 256*16*256*2       -> ends 4845568
#define OFF_C2P    ((size_t)4845568)    // code2 nibble-packed: 25088*128 -> ends 8056832
#define OFF_OUT1   ((size_t)8056832)    // 25088*256 f64 (encode-feeding: f64!) -> ends 59437056
#define OFF_SC     ((size_t)59437056)   // 25088*256 f32 -> ends 85127168
#define OFF_OUT2   ((size_t)85127168)   // 25088*256 f32 -> ends 110817280 (< proven 113274880)

__device__ inline float bf_lo(u32 p){ union{u32 u; float f;} t; t.u = p << 16;        return t.f; }
__device__ inline float bf_hi(u32 p){ union{u32 u; float f;} t; t.u = p & 0xFFFF0000u; return t.f; }
__device__ inline u32 rne_bf16(float f){ union{float f; u32 u;} t; t.f = f; return (t.u + 0x7FFFu + ((t.u >> 16) & 1u)) >> 16; }

// ---------------- f32 -> bf16 LUT conversion (lut2 then lut_s) ----------------
__global__ __launch_bounds__(256) void k_cvt(const float* __restrict__ lut2, const float* __restrict__ lut_s,
                                             u32* __restrict__ d2, u32* __restrict__ ds_) {
  int i = blockIdx.x*256 + threadIdx.x;     // one thread = 4 floats -> uint2 (8B)
  float4 v; uint2* dst; int base;
  if (i < 262144) { v = ((const float4*)lut2)[i];          dst = (uint2*)d2;  base = i; }
  else            { v = ((const float4*)lut_s)[i - 262144]; dst = (uint2*)ds_; base = i - 262144; }
  uint2 o;
  o.x = rne_bf16(v.x) | (rne_bf16(v.y) << 16);
  o.y = rne_bf16(v.z) | (rne_bf16(v.w) << 16);
  dst[base] = o;
}

// ---------------- BN1 stats (f64) ----------------
__global__ __launch_bounds__(256) void k_bn1_stats(const float* __restrict__ x,
                                                   double* __restrict__ s1, double* __restrict__ q1) {
  __shared__ double rs[256], rq[256];
  int b = blockIdx.x; int c = b >> 3, chunk = b & 7;
  int tid = threadIdx.x;
  double s = 0.0, q = 0.0;
  for (int nn = chunk*4; nn < chunk*4 + 4; ++nn) {
    const float* p = x + (size_t)nn*CHW1 + (size_t)c*HW1;
    for (int i = tid; i < HW1; i += 256) { double v = (double)p[i]; s += v; q += v*v; }
  }
  rs[tid] = s; rq[tid] = q; __syncthreads();
  for (int st = 128; st > 0; st >>= 1) {
    if (tid < st) { rs[tid] += rs[tid+st]; rq[tid] += rq[tid+st]; }
    __syncthreads();
  }
  if (tid == 0) { atomicAdd(&s1[c], rs[0]); atomicAdd(&q1[c], rq[0]); }
}

// ---------------- BN finalize -> per-channel scale/shift (f64) ----------------
__global__ __launch_bounds__(256) void k_fin(const double* __restrict__ s, const double* __restrict__ q,
                                             const float* __restrict__ g, const float* __restrict__ b,
                                             double* __restrict__ scale, double* __restrict__ shift,
                                             int nc, double cnt) {
  int c = blockIdx.x*blockDim.x + threadIdx.x;
  if (c >= nc) return;
  double m   = s[c] / cnt;
  double var = q[c] / cnt - m*m;
  double istd = 1.0 / sqrt(var + 1e-5);
  double sc = istd * (double)g[c];
  scale[c] = sc;
  shift[c] = (double)b[c] - m*sc;
}

// ---------------- encode conv1 (nibble-packed) + shortcut ----------------
__global__ __launch_bounds__(256) void k_enc1(const float* __restrict__ x,
                                              const int* __restrict__ sd1, const float* __restrict__ thr1,
                                              const int* __restrict__ sds, const float* __restrict__ thrs,
                                              const double* __restrict__ scale1, const double* __restrict__ shift1,
                                              u8* __restrict__ c1p, u8* __restrict__ codes) {
  __shared__ double lsc[C1], lsh[C1];
  __shared__ float lthr[32*15];
  __shared__ u8 lsd[32][4];
  int tid = threadIdx.x;
  int y = blockIdx.y;                    // 0..3: conv1 channel chunks; 4: shortcut
  int cbase = (y < 4) ? y*32 : 0;
  if (tid < C1) { lsc[tid] = scale1[tid]; lsh[tid] = shift1[tid]; }
  if (y < 4) {
    for (int i = tid; i < 32*15; i += 256) lthr[i] = thr1[cbase*15 + i];
    if (tid < 32) for (int j = 0; j < 4; ++j) lsd[tid][j] = (u8)sd1[(cbase+tid)*4 + j];
  } else {
    for (int i = tid; i < 32*15; i += 256) lthr[i] = thrs[i];
    if (tid < 32) for (int j = 0; j < 4; ++j) lsd[tid][j] = (u8)sds[tid*4 + j];
  }
  __syncthreads();
  int r = blockIdx.x*256 + tid;
  int n = r / OHW; int rem = r % OHW; int ho = rem / WO; int wo = rem % WO;
  const float* xn = x + (size_t)n*CHW1;
  if (y < 4) {
    u64 w0 = 0, w1 = 0;
    for (int ci = 0; ci < 32; ++ci) {
      int c = cbase + ci;
      double sc = lsc[c], sh = lsh[c];
      int code = 0;
      #pragma unroll
      for (int t = 0; t < 4; ++t) {
        int sd = lsd[ci][t];             // 0..8
        int kh = sd / 3, kw = sd - kh*3;
        int ih = 2*ho + kh - 1, iw = 2*wo + kw - 1;
        double thr = (double)lthr[ci*15 + ((1<<t)-1) + code];
        int bit;
        if ((unsigned)ih < (unsigned)H1 && (unsigned)iw < (unsigned)W1) {
          double z = fma((double)xn[c*HW1 + ih*W1 + iw], sc, sh);
          z = z > 0.0 ? z : 0.0;         // relu
          bit = (z > thr) ? 1 : 0;
        } else {
          bit = (0.0 > thr) ? 1 : 0;     // zero padding participates in compare
        }
        code = code + code + bit;
      }
      u64 cc = (u64)code << (4*(ci & 15));
      if (ci < 16) w0 |= cc; else w1 |= cc;
    }
    ulonglong2 pk; pk.x = w0; pk.y = w1;
    *(ulonglong2*)(c1p + (size_t)r*64 + (cbase >> 1)) = pk;
  } else {
    int base = (2*ho)*W1 + 2*wo;
    for (int ci = 0; ci < 32; ++ci) {
      int code = 0;
      #pragma unroll
      for (int t = 0; t < 4; ++t) {
        int sd = lsd[ci][t];             // 0..3 -> channel within group
        int ch = ci*4 + sd;
        double thr = (double)lthr[ci*15 + ((1<<t)-1) + code];
        double z = fma((double)xn[ch*HW1 + base], lsc[ch], lsh[ch]);
        z = z > 0.0 ? z : 0.0;
        int bit = (z > thr) ? 1 : 0;
        code = code + code + bit;
      }
      codes[(size_t)r*32 + ci] = (u8)code;
    }
  }
}

// ---------------- gather conv1 (f32 LUT, f64 acc) + shortcut (bf16 LUT) + fused BN2 stats ----------------
__global__ __launch_bounds__(256) void k_gather1(const u8* __restrict__ c1p, const u8* __restrict__ codes,
                                                 const float* __restrict__ lut1, const uint2* __restrict__ lutS16,
                                                 double* __restrict__ out1, float* __restrict__ sc,
                                                 double* __restrict__ s2, double* __restrict__ q2) {
  __shared__ double red[4][256];
  int tid = threadIdx.x;
  int l = tid & 63;
  int wid = tid >> 6;
  int r = blockIdx.x*4 + wid;
  const u32* cp = (const u32*)(c1p + (size_t)r*64);
  const float4* L = (const float4*)lut1;
  double a0=0,a1=0,a2=0,a3=0;
  #pragma unroll 2
  for (int w = 0; w < 16; ++w) {
    u32 cv = cp[w];
    #pragma unroll
    for (int j = 0; j < 8; ++j) {
      int c = w*8 + j;
      int code = (cv >> (4*j)) & 15;
      float4 v = L[((c*16 + code) << 6) + l];
      a0 += (double)v.x; a1 += (double)v.y; a2 += (double)v.z; a3 += (double)v.w;
    }
  }
  // shortcut: bf16 LUT
  float b0=0,b1=0,b2=0,b3=0;
  const u32* cps = (const u32*)(codes + (size_t)r*32);
  #pragma unroll
  for (int w = 0; w < 8; ++w) {
    u32 cv = cps[w];
    #pragma unroll
    for (int j = 0; j < 4; ++j) {
      int c = w*4 + j;
      int code = (cv >> (8*j)) & 15;
      uint2 v = lutS16[((c*16 + code) << 6) + l];
      b0 += bf_lo(v.x); b1 += bf_hi(v.x); b2 += bf_lo(v.y); b3 += bf_hi(v.y);
    }
  }
  size_t o = (size_t)r*C2 + l*4;
  double2 d0; d0.x=a0; d0.y=a1;
  double2 d1; d1.x=a2; d1.y=a3;
  *(double2*)(out1 + o)     = d0;
  *(double2*)(out1 + o + 2) = d1;
  float4 bb; bb.x=b0; bb.y=b1; bb.z=b2; bb.w=b3;
  *(float4*)(sc + o) = bb;
  // fused BN2 stats: per-channel sums over the block's 4 rows, then f64 atomics
  red[wid][l*4+0]=a0; red[wid][l*4+1]=a1; red[wid][l*4+2]=a2; red[wid][l*4+3]=a3;
  __syncthreads();
  double s = red[0][tid] + red[1][tid] + red[2][tid] + red[3][tid];
  atomicAdd(&s2[tid], s);
  __syncthreads();
  red[wid][l*4+0]=a0*a0; red[wid][l*4+1]=a1*a1; red[wid][l*4+2]=a2*a2; red[wid][l*4+3]=a3*a3;
  __syncthreads();
  double q = red[0][tid] + red[1][tid] + red[2][tid] + red[3][tid];
  atomicAdd(&q2[tid], q);
}

// ---------------- encode conv2 from f64 out1 (nibble-packed output) ----------------
__global__ __launch_bounds__(256) void k_enc2(const double* __restrict__ out1,
                                              const int* __restrict__ sd2, const float* __restrict__ thr2,
                                              const double* __restrict__ scale2, const double* __restrict__ shift2,
                                              u8* __restrict__ c2p) {
  __shared__ float lthr[C2*15];
  __shared__ u8 lsd[C2][4];
  __shared__ double lsc[C2], lsh[C2];
  int tid = threadIdx.x;
  for (int i = tid; i < C2*15; i += 256) lthr[i] = thr2[i];
  for (int j = 0; j < 4; ++j) lsd[tid][j] = (u8)sd2[tid*4 + j];
  lsc[tid] = scale2[tid]; lsh[tid] = shift2[tid];
  __syncthreads();
  int c = tid;
  double scv = lsc[c], shv = lsh[c];
  int r0 = blockIdx.x*8;
  for (int rr = 0; rr < 8; ++rr) {
    int r = r0 + rr;
    int n = r / OHW; int rem = r % OHW; int ho = rem / WO; int wo = rem % WO;
    const double* on = out1 + (size_t)n*OHW*C2;
    int code = 0;
    #pragma unroll
    for (int t = 0; t < 4; ++t) {
      int sd = lsd[c][t];
      int kh = sd / 3, kw = sd - kh*3;
      int h = ho + kh - 1, w = wo + kw - 1;
      double thr = (double)lthr[c*15 + ((1<<t)-1) + code];
      int bit;
      if ((unsigned)h < (unsigned)HO && (unsigned)w < (unsigned)WO) {
        double z = fma(on[(size_t)(h*WO + w)*C2 + c], scv, shv);
        z = z > 0.0 ? z : 0.0;
        bit = (z > thr) ? 1 : 0;
      } else {
        bit = (0.0 > thr) ? 1 : 0;
      }
      code = code + code + bit;
    }
    int partner = __shfl_xor(code, 1);
    if (!(tid & 1)) c2p[(size_t)r*128 + (c >> 1)] = (u8)(code | (partner << 4));
  }
}

// ---------------- gather conv2 (bf16 LUT) + fused pool ----------------
__global__ __launch_bounds__(256) void k_gather2(const u8* __restrict__ c2p,
                                                 const uint2* __restrict__ lut216,
                                                 float* __restrict__ out2, float* __restrict__ pool) {
  __shared__ float red[4][256];
  int tid = threadIdx.x;
  int l = tid & 63;
  int wid = tid >> 6;
  int r = blockIdx.x*4 + wid;
  const u32* cp = (const u32*)(c2p + (size_t)r*128);
  float a0=0,a1=0,a2=0,a3=0;
  #pragma unroll 2
  for (int w = 0; w < 32; ++w) {
    u32 cv = cp[w];
    #pragma unroll
    for (int j = 0; j < 8; ++j) {
      int c = w*8 + j;
      int code = (cv >> (4*j)) & 15;
      uint2 v = lut216[((c*16 + code) << 6) + l];
      a0 += bf_lo(v.x); a1 += bf_hi(v.x); a2 += bf_lo(v.y); a3 += bf_hi(v.y);
    }
  }
  float4 res; res.x=a0; res.y=a1; res.z=a2; res.w=a3;
  *(float4*)(out2 + (size_t)r*C2 + l*4) = res;
  // fused global-avg-pool partial sums (all 4 rows in block share n: 784 % 4 == 0)
  int n = blockIdx.x / 196;
  red[wid][l*4+0]=a0; red[wid][l*4+1]=a1; red[wid][l*4+2]=a2; red[wid][l*4+3]=a3;
  __syncthreads();
  float p = red[0][tid] + red[1][tid] + red[2][tid] + red[3][tid];
  atomicAdd(&pool[n*C2 + tid], p);
}

// ---------------- SE gate: fc1 -> relu -> fc2 -> sigmoid ----------------
__global__ __launch_bounds__(256) void k_se(const float* __restrict__ pool,
                                            const float* __restrict__ w1, const float* __restrict__ b1f,
                                            const float* __restrict__ w2, const float* __restrict__ b2f,
                                            float* __restrict__ gate) {
  __shared__ float lp[C2];
  __shared__ float lh[16];
  int n = blockIdx.x, tid = threadIdx.x;
  lp[tid] = pool[n*C2 + tid] * (1.0f/(float)OHW);
  __syncthreads();
  if (tid < 16) {
    float s = b1f[tid];
    for (int c = 0; c < C2; ++c) s += lp[c]*w1[tid*C2 + c];
    lh[tid] = s > 0.0f ? s : 0.0f;
  }
  __syncthreads();
  float s = b2f[tid];
  #pragma unroll
  for (int i = 0; i < 16; ++i) s += lh[i]*w2[tid*16 + i];
  gate[n*C2 + tid] = 1.0f/(1.0f + expf(-s));
}

// ---------------- final: out = out2*gate + shortcut, NHWC -> NCHW via LDS tile ----------------
__global__ __launch_bounds__(256) void k_final(const float* __restrict__ out2, const float* __restrict__ scv,
                                               const float* __restrict__ gate, float* __restrict__ outp) {
  __shared__ float tile[64][113];
  int n = blockIdx.x, chb = blockIdx.y, pxb = blockIdx.z;
  int l = threadIdx.x & 63, w4 = threadIdx.x >> 6;
  float g = gate[n*C2 + chb*64 + l];
  int pxbase = pxb*112;
  #pragma unroll 4
  for (int i = 0; i < 28; ++i) {
    int px = i*4 + w4;
    size_t rc = ((size_t)(n*OHW + pxbase + px))*C2 + chb*64 + l;
    tile[l][px] = out2[rc]*g + scv[rc];
  }
  __syncthreads();
  #pragma unroll 4
  for (int j = 0; j < 28; ++j) {
    int flat = j*256 + threadIdx.x;
    int ch = flat / 112, px = flat - ch*112;
    outp[((size_t)(n*C2 + chb*64 + ch))*OHW + pxbase + px] = tile[ch][px];
  }
}

extern "C" void kernel_launch(void* const* d_in, const int* in_sizes, int n_in,
                              void* d_out, int out_size, void* d_ws, size_t ws_size,
                              hipStream_t stream) {
  const float* x     = (const float*)d_in[0];
  const float* bn1_g = (const float*)d_in[1];
  const float* bn1_b = (const float*)d_in[2];
  const float* bn2_g = (const float*)d_in[3];
  const float* bn2_b = (const float*)d_in[4];
  const float* thr1  = (const float*)d_in[5];
  const float* lut1  = (const float*)d_in[6];
  const float* thr2  = (const float*)d_in[7];
  const float* lut2  = (const float*)d_in[8];
  const float* thr_s = (const float*)d_in[9];
  const float* lut_s = (const float*)d_in[10];
  const float* fc1_w = (const float*)d_in[11];
  const float* fc1_b = (const float*)d_in[12];
  const float* fc2_w = (const float*)d_in[13];
  const float* fc2_b = (const float*)d_in[14];
  const int*   sd1   = (const int*)d_in[15];
  const int*   sd2   = (const int*)d_in[16];
  const int*   sd_s  = (const int*)d_in[17];

  char* ws = (char*)d_ws;
  double* bn1s  = (double*)(ws + OFF_BN1S);
  double* bn1q  = (double*)(ws + OFF_BN1Q);
  double* bn2s  = (double*)(ws + OFF_BN2S);
  double* bn2q  = (double*)(ws + OFF_BN2Q);
  float*  pool  = (float*)(ws + OFF_POOL);
  double* scale1= (double*)(ws + OFF_SCALE1);
  double* shift1= (double*)(ws + OFF_SHIFT1);
  double* scale2= (double*)(ws + OFF_SCALE2);
  double* shift2= (double*)(ws + OFF_SHIFT2);
  float*  gate  = (float*)(ws + OFF_GATE);
  u8*     c1p   = (u8*)(ws + OFF_C1P);
  u8*     codes = (u8*)(ws + OFF_CS);
  u32*    ls16  = (u32*)(ws + OFF_LS16);
  u32*    l216  = (u32*)(ws + OFF_L216);
  u8*     c2p   = (u8*)(ws + OFF_C2P);
  double* out1  = (double*)(ws + OFF_OUT1);
  float*  scb   = (float*)(ws + OFF_SC);
  float*  out2  = (float*)(ws + OFF_OUT2);
  float*  outp  = (float*)d_out;

  // zero the accumulators (bn sums + pool); ws is poisoned before every call
  hipMemsetAsync(ws, 0, 38912, stream);

  k_cvt<<<1152, 256, 0, stream>>>(lut2, lut_s, l216, ls16);
  k_bn1_stats<<<1024, 256, 0, stream>>>(x, bn1s, bn1q);
  k_fin<<<1, 128, 0, stream>>>(bn1s, bn1q, bn1_g, bn1_b, scale1, shift1, C1, (double)(N_*HW1));
  k_enc1<<<dim3(98, 5), 256, 0, stream>>>(x, sd1, thr1, sd_s, thr_s, scale1, shift1, c1p, codes);
  k_gather1<<<R_/4, 256, 0, stream>>>(c1p, codes, lut1, (const uint2*)ls16, out1, scb, bn2s, bn2q);
  k_fin<<<1, 256, 0, stream>>>(bn2s, bn2q, bn2_g, bn2_b, scale2, shift2, C2, (double)R_);
  k_enc2<<<R_/8, 256, 0, stream>>>(out1, sd2, thr2, scale2, shift2, c2p);
  k_gather2<<<R_/4, 256, 0, stream>>>(c2p, (const uint2*)l216, out2, pool);
  k_se<<<N_, 256, 0, stream>>>(pool, fc1_w, fc1_b, fc2_w, fc2_b, gate);
  k_final<<<dim3(N_, 4, 7), 256, 0, stream>>>(out2, scb, gate, outp);
}